// Round 4
// baseline (137.285 us; speedup 1.0000x reference)
//
#include <hip/hip_runtime.h>
#include <hip/hip_bf16.h>

#define N_NODES 2048
#define EMB 768
#define NH 8
#define DH 96
#define ALPHA 0.2f
#define SCALE 0.10206207261596575f  // 96^-0.5
#define NGMAX 192
#define WSZ (EMB * EMB)

typedef __bf16 bf16x8 __attribute__((ext_vector_type(8)));
typedef float f32x4 __attribute__((ext_vector_type(4)));
typedef __attribute__((address_space(3))) unsigned int lds_u32;
typedef __attribute__((address_space(1))) const unsigned int glb_u32;

union pack4 { ushort4 u; __hip_bfloat16 h[4]; };

// ---------------------------------------------------------------- prep: concat-cast e + cast 3 weights + zero cnt
// (R0-verified version, unchanged)
__global__ __launch_bounds__(256) void prep_kernel(
    const float* __restrict__ eh, const float* __restrict__ er, const float* __restrict__ et,
    const float* __restrict__ W0, const float* __restrict__ W1, const float* __restrict__ W2,
    __hip_bfloat16* __restrict__ e, __hip_bfloat16* __restrict__ o0,
    __hip_bfloat16* __restrict__ o1, __hip_bfloat16* __restrict__ o2, int* __restrict__ cnt)
{
    const int b = blockIdx.x;
    const int gtid = b * 256 + threadIdx.x;
    if (gtid < 32) cnt[gtid] = 0;
    const float* src;
    __hip_bfloat16* dst;
    if (b < 1536) {                       // e = concat(eh,er,et)
        int idx = gtid * 4;
        int i = idx / EMB, c = idx % EMB;
        if (c < 256)      src = eh + i * 256 + c;
        else if (c < 512) src = er + i * 256 + (c - 256);
        else              src = et + i * 256 + (c - 512);
        dst = e + (size_t)i * EMB + c;
    } else {                              // three 768x768 weights
        int idx = (gtid - 1536 * 256) * 4;
        if (idx < WSZ)          { src = W0 + idx;           dst = o0 + idx; }
        else if (idx < 2 * WSZ) { src = W1 + idx - WSZ;     dst = o1 + idx - WSZ; }
        else                    { src = W2 + idx - 2 * WSZ; dst = o2 + idx - 2 * WSZ; }
    }
    float4 v = *reinterpret_cast<const float4*>(src);
    pack4 p;
    p.h[0] = __float2bfloat16(v.x);
    p.h[1] = __float2bfloat16(v.y);
    p.h[2] = __float2bfloat16(v.z);
    p.h[3] = __float2bfloat16(v.w);
    *reinterpret_cast<ushort4*>(dst) = p.u;
}

// ---------------------------------------------------------------- counted-vmcnt ring-3 MFMA GEMM
// C = A@B^T (+bias / +=), row-major ld=EMB, M=2048, K=768. Per block-column select:
//   blockIdx.x <  nbn1 : C1 (no bias)   blockIdx.x >= nbn1 : C2 (+bias1+bias2)
// Tile 128(M)x64(N), BK=64, 12 stages, 4 waves (2x2), each wave 64x32 (4x2 frags).
// Ring-3 LDS (72 KB), depth-1 prefetch, s_waitcnt vmcnt(6) + raw s_barrier per stage
// (loads for stage s+1 stay in flight across the barrier — no vmcnt(0) drain in loop).
// Buffer safety: writer(stage s+1) vs readers(stage s-2) separated by iter s-1 barrier.
// Staging: BK=64 XOR swizzle (R1-proven): chunk (row,cb) stored at row*8 + (cb^(row&7)),
// linear LDS dest (global_load_lds requirement), pre-swizzled global source.
__device__ __forceinline__ void stageA64(
    const __hip_bfloat16* __restrict__ src, int row0, int k0,
    __hip_bfloat16* lds, int wave, int lane)
{
#pragma unroll
    for (int i = 0; i < 4; i++) {                 // 128 rows x 8 chunks = 1024 chunks
        const int c0 = wave * 256 + i * 64;
        const int c = c0 + lane;
        const int row = c >> 3;
        const int cb = (c & 7) ^ (row & 7);
        const __hip_bfloat16* g = src + (size_t)(row0 + row) * EMB + k0 + cb * 8;
        __builtin_amdgcn_global_load_lds((glb_u32*)g, (lds_u32*)(lds + c0 * 8), 16, 0, 0);
    }
}
__device__ __forceinline__ void stageB64(
    const __hip_bfloat16* __restrict__ src, int row0, int k0,
    __hip_bfloat16* lds, int wave, int lane)
{
#pragma unroll
    for (int i = 0; i < 2; i++) {                 // 64 rows x 8 chunks = 512 chunks
        const int c0 = wave * 128 + i * 64;
        const int c = c0 + lane;
        const int row = c >> 3;
        const int cb = (c & 7) ^ (row & 7);
        const __hip_bfloat16* g = src + (size_t)(row0 + row) * EMB + k0 + cb * 8;
        __builtin_amdgcn_global_load_lds((glb_u32*)g, (lds_u32*)(lds + c0 * 8), 16, 0, 0);
    }
}

__global__ __launch_bounds__(256) void gemm_kernel(
    const __hip_bfloat16* __restrict__ A,
    const __hip_bfloat16* __restrict__ B1, const __hip_bfloat16* __restrict__ B2,
    const float* __restrict__ bias1, const float* __restrict__ bias2,
    float* __restrict__ C1, float* __restrict__ C2,
    int nbn1, int accum)
{
    __shared__ __attribute__((aligned(16))) __hip_bfloat16 smA[3][8192]; // 3 x 128x64
    __shared__ __attribute__((aligned(16))) __hip_bfloat16 smB[3][4096]; // 3 x  64x64

    const int t = threadIdx.x;
    const int lane = t & 63, wave = t >> 6;
    const int wm = wave >> 1, wn = wave & 1;
    const int bnb = blockIdx.x;
    const bool second = bnb >= nbn1;
    const __hip_bfloat16* B = second ? B2 : B1;
    float* Cf = second ? C2 : C1;
    const int bn = (second ? bnb - nbn1 : bnb) * 64;
    const int bm = blockIdx.y * 128;
    const int l15 = lane & 15, quad = lane >> 4;

    f32x4 acc00 = {0,0,0,0}, acc01 = {0,0,0,0};
    f32x4 acc10 = {0,0,0,0}, acc11 = {0,0,0,0};
    f32x4 acc20 = {0,0,0,0}, acc21 = {0,0,0,0};
    f32x4 acc30 = {0,0,0,0}, acc31 = {0,0,0,0};

    const int ra0 = wm * 64 + l15;                 // A fragment rows (+0,16,32,48)
    const int rb0 = wn * 32 + l15;                 // B fragment rows (+0,16)
    const int xa = ra0 & 7;                        // (ra0+16k)&7 == ra0&7
    const int xb = rb0 & 7;

    stageA64(A, bm, 0, &smA[0][0], wave, lane);
    stageB64(B, bn, 0, &smB[0][0], wave, lane);

    int bufc = 0;
#pragma unroll 1
    for (int s = 0; s < 12; s++) {
        const int bufn = (bufc == 2) ? 0 : bufc + 1;
        if (s + 1 < 12) {
            const int k0 = (s + 1) * 64;
            stageA64(A, bm, k0, &smA[bufn][0], wave, lane);
            stageB64(B, bn, k0, &smB[bufn][0], wave, lane);
            asm volatile("s_waitcnt vmcnt(6)" ::: "memory");   // stage s resident; s+1 in flight
        } else {
            asm volatile("s_waitcnt vmcnt(0)" ::: "memory");
        }
        __builtin_amdgcn_s_barrier();

        const __hip_bfloat16* At = &smA[bufc][0];
        const __hip_bfloat16* Bt = &smB[bufc][0];
#pragma unroll
        for (int ks = 0; ks < 2; ks++) {
            const int cq = ks * 4 + quad;
            bf16x8 a0 = *(const bf16x8*)(At + (size_t)((ra0     ) * 8 + (cq ^ xa)) * 8);
            bf16x8 a1 = *(const bf16x8*)(At + (size_t)((ra0 + 16) * 8 + (cq ^ xa)) * 8);
            bf16x8 a2 = *(const bf16x8*)(At + (size_t)((ra0 + 32) * 8 + (cq ^ xa)) * 8);
            bf16x8 a3 = *(const bf16x8*)(At + (size_t)((ra0 + 48) * 8 + (cq ^ xa)) * 8);
            bf16x8 b0 = *(const bf16x8*)(Bt + (size_t)((rb0     ) * 8 + (cq ^ xb)) * 8);
            bf16x8 b1 = *(const bf16x8*)(Bt + (size_t)((rb0 + 16) * 8 + (cq ^ xb)) * 8);
            acc00 = __builtin_amdgcn_mfma_f32_16x16x32_bf16(a0, b0, acc00, 0, 0, 0);
            acc01 = __builtin_amdgcn_mfma_f32_16x16x32_bf16(a0, b1, acc01, 0, 0, 0);
            acc10 = __builtin_amdgcn_mfma_f32_16x16x32_bf16(a1, b0, acc10, 0, 0, 0);
            acc11 = __builtin_amdgcn_mfma_f32_16x16x32_bf16(a1, b1, acc11, 0, 0, 0);
            acc20 = __builtin_amdgcn_mfma_f32_16x16x32_bf16(a2, b0, acc20, 0, 0, 0);
            acc21 = __builtin_amdgcn_mfma_f32_16x16x32_bf16(a2, b1, acc21, 0, 0, 0);
            acc30 = __builtin_amdgcn_mfma_f32_16x16x32_bf16(a3, b0, acc30, 0, 0, 0);
            acc31 = __builtin_amdgcn_mfma_f32_16x16x32_bf16(a3, b1, acc31, 0, 0, 0);
        }
        bufc = bufn;
    }

    const int col0 = bn + wn * 32 + l15;
    const int col1 = col0 + 16;
    float bv0 = 0.f, bv1 = 0.f;
    if (second && bias1 != nullptr) {
        bv0 = bias1[col0] + bias2[col0];
        bv1 = bias1[col1] + bias2[col1];
    }
    const int r0 = bm + wm * 64 + quad * 4;
#pragma unroll
    for (int r = 0; r < 4; r++) {
        const int rw0 = r0 + r, rw1 = rw0 + 16, rw2 = rw0 + 32, rw3 = rw0 + 48;
        float* p00 = &Cf[(size_t)rw0 * EMB + col0]; float* p01 = &Cf[(size_t)rw0 * EMB + col1];
        float* p10 = &Cf[(size_t)rw1 * EMB + col0]; float* p11 = &Cf[(size_t)rw1 * EMB + col1];
        float* p20 = &Cf[(size_t)rw2 * EMB + col0]; float* p21 = &Cf[(size_t)rw2 * EMB + col1];
        float* p30 = &Cf[(size_t)rw3 * EMB + col0]; float* p31 = &Cf[(size_t)rw3 * EMB + col1];
        if (accum) {       // exclusive ownership: plain load+add+store, no atomics
            *p00 += acc00[r]; *p01 += acc01[r];
            *p10 += acc10[r]; *p11 += acc11[r];
            *p20 += acc20[r]; *p21 += acc21[r];
            *p30 += acc30[r]; *p31 += acc31[r];
        } else {
            *p00 = acc00[r] + bv0; *p01 = acc01[r] + bv1;
            *p10 = acc10[r] + bv0; *p11 = acc11[r] + bv1;
            *p20 = acc20[r] + bv0; *p21 = acc21[r] + bv1;
            *p30 = acc30[r] + bv0; *p31 = acc31[r] + bv1;
        }
    }
}

// ---------------------------------------------------------------- s1/s2 + group lists (R0-verified version, unchanged)
__global__ __launch_bounds__(256) void s12g_kernel(
    const float* __restrict__ Wh, const float* __restrict__ a,
    float* __restrict__ s1, float* __restrict__ s2,
    const int* __restrict__ h_id, int* __restrict__ cnt, int* __restrict__ lists)
{
    int gid = blockIdx.x * 256 + threadIdx.x;  // [0, N*NH)
    if (gid < N_NODES) {
        int g = h_id[gid];
        int p = atomicAdd(&cnt[g], 1);
        lists[g * N_NODES + p] = gid;
    }
    int i = gid >> 3, h = gid & 7;
    const float* wr = Wh + (size_t)i * EMB + h * DH;
    float acc1 = 0.f, acc2 = 0.f;
    for (int d = 0; d < DH; d++) {
        float w = wr[d];
        acc1 += w * a[d];
        acc2 += w * a[DH + d];
    }
    s1[gid] = acc1;
    s2[gid] = acc2;
}

// ---------------------------------------------------------------- attention: block per (group, head, col-half)
// rows split across 2 thread-halves (t>>7) each owning 24 of the 48 cols -> 2x active lanes in PV.
__global__ __launch_bounds__(256) void attn_kernel(
    const float* __restrict__ Wh, const float* __restrict__ s1, const float* __restrict__ s2,
    const int* __restrict__ cnt, const int* __restrict__ lists,
    __hip_bfloat16* __restrict__ out)
{
    const int g  = blockIdx.x & 31;
    const int h  = (blockIdx.x >> 5) & 7;
    const int dh = blockIdx.x >> 8;          // 0/1 -> cols [dh*48, dh*48+48)
    const int t  = threadIdx.x;

    __shared__ int   jb[NGMAX];
    __shared__ int   qg[NGMAX];
    __shared__ float s2g[NGMAX];
    __shared__ float s1g[NGMAX][9];          // pad 9: stride-8 would 16-way conflict
    __shared__ float Whg[NGMAX][48];

    const int ng = min(cnt[g], NGMAX);
    const int* gl = lists + g * N_NODES;

    for (int j = t; j < ng; j += 256) {
        int node = gl[j];
        jb[j]  = node;
        qg[j]  = node >> 8;
        s2g[j] = s2[node * 8 + h];
        float4 v0 = *reinterpret_cast<const float4*>(s1 + node * 8);
        float4 v1 = *reinterpret_cast<const float4*>(s1 + node * 8 + 4);
        s1g[j][0] = v0.x; s1g[j][1] = v0.y; s1g[j][2] = v0.z; s1g[j][3] = v0.w;
        s1g[j][4] = v1.x; s1g[j][5] = v1.y; s1g[j][6] = v1.z; s1g[j][7] = v1.w;
    }
    __syncthreads();
    for (int idx = t; idx < ng * 12; idx += 256) {
        int jc = idx / 12, dq = idx % 12;
        float4 v = *reinterpret_cast<const float4*>(
            Wh + (size_t)jb[jc] * EMB + h * DH + dh * 48 + dq * 4);
        *reinterpret_cast<float4*>(&Whg[jc][dq * 4]) = v;
    }
    __syncthreads();

    const int half = t >> 7;
    const int d0 = half * 24;
    for (int tr = t & 127; tr < ng; tr += 128) {
        float m = -1e30f;
        for (int j = 0; j < ng; j++) {
            float x = s1g[tr][qg[j]] + s2g[j];
            float ev = (x >= 0.f ? x : ALPHA * x) * SCALE;
            m = fmaxf(m, ev);
        }
        float S = 0.f;
        for (int j = 0; j < ng; j++) {
            float x = s1g[tr][qg[j]] + s2g[j];
            float ev = (x >= 0.f ? x : ALPHA * x) * SCALE;
            S += __expf(ev - m);
        }
        const float ri = 1.f / S;

        float acc[24];
#pragma unroll
        for (int d = 0; d < 24; d++) acc[d] = 0.f;
        for (int j = 0; j < ng; j++) {
            float x = s1g[tr][qg[j]] + s2g[j];
            float ev = (x >= 0.f ? x : ALPHA * x) * SCALE;
            float p = __expf(ev - m) * ri;
#pragma unroll
            for (int d = 0; d < 24; d++) acc[d] += p * Whg[j][d0 + d];
        }
        __hip_bfloat16* po = out + (size_t)jb[tr] * EMB + h * DH + dh * 48 + d0;
#pragma unroll
        for (int d = 0; d < 24; d += 4) {
            pack4 pk;
            pk.h[0] = __float2bfloat16(acc[d]);
            pk.h[1] = __float2bfloat16(acc[d + 1]);
            pk.h[2] = __float2bfloat16(acc[d + 2]);
            pk.h[3] = __float2bfloat16(acc[d + 3]);
            *reinterpret_cast<ushort4*>(po + d) = pk.u;
        }
    }
}

// ---------------------------------------------------------------- launch
extern "C" void kernel_launch(void* const* d_in, const int* in_sizes, int n_in,
                              void* d_out, int out_size, void* d_ws, size_t ws_size,
                              hipStream_t stream)
{
    const float* eh     = (const float*)d_in[0];
    const float* er     = (const float*)d_in[1];
    const float* et     = (const float*)d_in[2];
    const int*   h_id   = (const int*)d_in[3];
    const float* W_w    = (const float*)d_in[4];
    const float* a      = (const float*)d_in[5];
    const float* proj_w = (const float*)d_in[6];
    const float* proj_b = (const float*)d_in[7];
    const float* skip_w = (const float*)d_in[8];
    const float* skip_b = (const float*)d_in[9];
    float* out = (float*)d_out;   // reference output dtype is f32

    char* ws = (char*)d_ws;
    __hip_bfloat16* e_ws   = (__hip_bfloat16*)(ws);              // 3,145,728 B
    float*          Wh_ws  = (float*)(ws + 3145728);             // 6,291,456 B
    __hip_bfloat16* at_ws  = (__hip_bfloat16*)(ws + 9437184);    // 3,145,728 B
    __hip_bfloat16* Wb_ws  = (__hip_bfloat16*)(ws + 12582912);   // 1,179,648 B
    __hip_bfloat16* Pb_ws  = (__hip_bfloat16*)(ws + 13762560);   // 1,179,648 B
    __hip_bfloat16* Sb_ws  = (__hip_bfloat16*)(ws + 14942208);   // 1,179,648 B
    float*          s1_ws  = (float*)(ws + 16121856);            //    65,536 B
    float*          s2_ws  = (float*)(ws + 16187392);            //    65,536 B
    int*            cnt_ws = (int*)(ws + 16252928);              //       128 B
    int*            lst_ws = (int*)(ws + 16253056);              //   262,144 B

    // casts + zero cnt (R0-exact)
    prep_kernel<<<3264, 256, 0, stream>>>(eh, er, et, W_w, proj_w, skip_w,
                                          e_ws, Wb_ws, Pb_ws, Sb_ws, cnt_ws);

    // Fused gemm1: Wh = e @ W_w^T (cols 0..11)  AND  out = e @ skip_w^T + (proj_b+skip_b) (cols 12..23)
    gemm_kernel<<<dim3(24, 16), 256, 0, stream>>>(
        e_ws, Wb_ws, Sb_ws, proj_b, skip_b, Wh_ws, out, 12, 0);

    s12g_kernel<<<64, 256, 0, stream>>>(Wh_ws, a, s1_ws, s2_ws, h_id, cnt_ws, lst_ws);

    attn_kernel<<<512, 256, 0, stream>>>(Wh_ws, s1_ws, s2_ws, cnt_ws, lst_ws, at_ws);

    // gemm2: out += at @ proj_w^T  (single stream, 12 stages, exclusive-ownership RMW)
    gemm_kernel<<<dim3(12, 16), 256, 0, stream>>>(
        at_ws, Pb_ws, nullptr, nullptr, nullptr, out, nullptr, 12, 1);
}